// Round 2
// baseline (1121.157 us; speedup 1.0000x reference)
//
#include <hip/hip_runtime.h>
#include <hip/hip_bf16.h>
#include <stdint.h>

// Problem constants (match reference)
#define N_NODES 50000
#define N_EDGES 300000
#define ET      3
#define D_IN    256
#define D_HID   256
#define D_OUT   128
#define KDIM    768   // ET * 256, fused-K for the single GEMM per layer

// ---------------------------------------------------------------------------
// CSR build: histogram -> per-etype exclusive scan -> fill sorted src lists
// ---------------------------------------------------------------------------

__global__ void hist_kernel(const int* __restrict__ edges, int* __restrict__ cnt) {
    int i = blockIdx.x * blockDim.x + threadIdx.x;
    if (i >= ET * N_EDGES) return;
    int e = i / N_EDGES;
    int j = i - e * N_EDGES;
    int dst = edges[(e * 2 + 1) * N_EDGES + j];
    atomicAdd(&cnt[e * N_NODES + dst], 1);
}

// One block (1024 threads) per etype. Writes exclusive-scan rowptr AND a
// cursor copy (fill bumps the cursor, rowptr stays pristine for the gather).
__global__ void scan_kernel(const int* __restrict__ cnt, int* __restrict__ rowptr,
                            int* __restrict__ cursor) {
    int e = blockIdx.x;
    const int* c = cnt + e * N_NODES;
    int* rp = rowptr + e * (N_NODES + 1);
    int* cu = cursor + e * N_NODES;
    int t = threadIdx.x, lane = t & 63, w = t >> 6;
    __shared__ int wsum[16];
    __shared__ int carry;
    if (t == 0) carry = 0;
    __syncthreads();
    for (int base = 0; base < N_NODES; base += 1024) {
        int i = base + t;
        int orig = (i < N_NODES) ? c[i] : 0;
        int v = orig;
        // wave-64 inclusive scan
        #pragma unroll
        for (int d = 1; d < 64; d <<= 1) {
            int u = __shfl_up(v, d, 64);
            if (lane >= d) v += u;
        }
        if (lane == 63) wsum[w] = v;
        __syncthreads();
        if (w == 0 && lane < 16) {
            int s = wsum[lane];
            #pragma unroll
            for (int d = 1; d < 16; d <<= 1) {
                int u = __shfl_up(s, d, 64);
                if (lane >= d) s += u;
            }
            wsum[lane] = s;
        }
        __syncthreads();
        int woff = (w > 0) ? wsum[w - 1] : 0;
        int excl = carry + woff + (v - orig);
        if (i < N_NODES) { rp[i] = excl; cu[i] = excl; }
        __syncthreads();            // everyone consumed carry/wsum
        if (t == 0) carry += wsum[15];
        __syncthreads();
    }
    if (t == 0) rp[N_NODES] = carry;   // == N_EDGES
}

__global__ void fill_kernel(const int* __restrict__ edges, int* __restrict__ cursor,
                            int* __restrict__ esrc) {
    int i = blockIdx.x * blockDim.x + threadIdx.x;
    if (i >= ET * N_EDGES) return;
    int e = i / N_EDGES;
    int j = i - e * N_EDGES;
    int src = edges[(e * 2 + 0) * N_EDGES + j];
    int dst = edges[(e * 2 + 1) * N_EDGES + j];
    int p = atomicAdd(&cursor[e * N_NODES + dst], 1);
    esrc[e * N_EDGES + p] = src;
}

// ---------------------------------------------------------------------------
// Aggregation (pull): one wave per (etype, node). Lane t owns channels
// [4t, 4t+4): a float4 per gathered row -> fully coalesced 1KB reads.
// Output layout xbar[n][e*256 + c] (row stride KDIM=768) so the projection
// is a single K=768 GEMM. Also emits ind[e][n] = (cnt>0) for the bias term.
// ---------------------------------------------------------------------------
__global__ void agg_kernel(const float* __restrict__ in, const int* __restrict__ rowptr,
                           const int* __restrict__ esrc, float* __restrict__ outbar,
                           float* __restrict__ ind) {
    int wid = (blockIdx.x * blockDim.x + threadIdx.x) >> 6;
    int lane = threadIdx.x & 63;
    if (wid >= ET * N_NODES) return;
    int e = wid / N_NODES;
    int n = wid - e * N_NODES;
    int r0 = rowptr[e * (N_NODES + 1) + n];
    int r1 = rowptr[e * (N_NODES + 1) + n + 1];
    int cntv = r1 - r0;
    float4 acc = make_float4(0.f, 0.f, 0.f, 0.f);
    const int* es = esrc + e * N_EDGES;
    for (int j = r0; j < r1; ++j) {
        int s = es[j];  // wave-uniform
        float4 v = *((const float4*)(in + (size_t)s * 256) + lane);
        acc.x += v.x; acc.y += v.y; acc.z += v.z; acc.w += v.w;
    }
    float sc = (cntv > 0) ? (1.f / (float)cntv) : 0.f;
    acc.x *= sc; acc.y *= sc; acc.z *= sc; acc.w *= sc;
    *((float4*)(outbar + (size_t)n * KDIM + e * 256) + lane) = acc;
    if (lane == 0) ind[e * N_NODES + n] = (cntv > 0) ? 1.f : 0.f;
}

// ---------------------------------------------------------------------------
// fp32 GEMM: out[M,Dout] = X[M,768] @ W'[Dout,768]^T  (+ per-etype bias*ind)
// W'[co][e*256+f] lives at W + (e*Dout + co)*256 + f (native W layout).
// 128x128 tile, BK=16, 256 threads, 8x8 micro-tile per thread as 2x2 blocks
// of 4x4 at (ty*4 / 64+ty*4) x (tx*4 / 64+tx*4) -> conflict-free b128 LDS
// reads (16 lanes cover 256 contiguous bytes).
// act=1 -> leaky_relu(0.01).
// ---------------------------------------------------------------------------
#define BM 128
#define BN 128
#define BK 16
#define LDP 132   // padded LDS row stride

__global__ __launch_bounds__(256) void gemm_kernel(
    const float* __restrict__ X, const float* __restrict__ W,
    const float* __restrict__ bias, const float* __restrict__ ind,
    float* __restrict__ out, int M, int Dout, int act) {
    __shared__ float As[BK][LDP];
    __shared__ float Bs[BK][LDP];
    int tid = threadIdx.x;
    int tx = tid & 15, ty = tid >> 4;
    int rb = blockIdx.x * BM;
    int cb = blockIdx.y * BN;

    float acc[8][8];
    #pragma unroll
    for (int i = 0; i < 8; ++i)
        #pragma unroll
        for (int j = 0; j < 8; ++j) acc[i][j] = 0.f;

    for (int k0 = 0; k0 < KDIM; k0 += BK) {
        int eidx = k0 >> 8;
        int fbase = k0 & 255;
        #pragma unroll
        for (int it = 0; it < 2; ++it) {
            int idx = tid + it * 256;          // 0..511
            int kk4 = (idx & 3) << 2;          // {0,4,8,12}
            int row = idx >> 2;                // 0..127
            int r = rb + row;
            float4 av = make_float4(0.f, 0.f, 0.f, 0.f);
            if (r < M) av = *(const float4*)(X + (size_t)r * KDIM + k0 + kk4);
            As[kk4 + 0][row] = av.x; As[kk4 + 1][row] = av.y;
            As[kk4 + 2][row] = av.z; As[kk4 + 3][row] = av.w;
            // B: co = row (BN==BM); always in-bounds (Dout % 128 == 0)
            float4 bv = *(const float4*)(W + ((size_t)eidx * Dout + (cb + row)) * 256 + fbase + kk4);
            Bs[kk4 + 0][row] = bv.x; Bs[kk4 + 1][row] = bv.y;
            Bs[kk4 + 2][row] = bv.z; Bs[kk4 + 3][row] = bv.w;
        }
        __syncthreads();
        #pragma unroll
        for (int kk = 0; kk < BK; ++kk) {
            float4 a0 = *(const float4*)&As[kk][ty * 4];
            float4 a1 = *(const float4*)&As[kk][64 + ty * 4];
            float4 b0 = *(const float4*)&Bs[kk][tx * 4];
            float4 b1 = *(const float4*)&Bs[kk][64 + tx * 4];
            float a[8] = {a0.x, a0.y, a0.z, a0.w, a1.x, a1.y, a1.z, a1.w};
            float b[8] = {b0.x, b0.y, b0.z, b0.w, b1.x, b1.y, b1.z, b1.w};
            #pragma unroll
            for (int i = 0; i < 8; ++i)
                #pragma unroll
                for (int j = 0; j < 8; ++j)
                    acc[i][j] = fmaf(a[i], b[j], acc[i][j]);
        }
        __syncthreads();
    }

    // epilogue: + sum_e ind[e][row] * bias[e][col], optional leaky_relu
    // cols: j=0..3 -> cb+tx*4+j ; j=4..7 -> cb+64+tx*4+(j-4)
    float bc[3][8];
    #pragma unroll
    for (int e = 0; e < 3; ++e)
        #pragma unroll
        for (int j = 0; j < 8; ++j) {
            int col = (j < 4) ? (cb + tx * 4 + j) : (cb + 64 + tx * 4 + j - 4);
            bc[e][j] = bias[e * Dout + col];
        }
    #pragma unroll
    for (int i = 0; i < 8; ++i) {
        int r = rb + ((i < 4) ? (ty * 4 + i) : (64 + ty * 4 + i - 4));
        if (r >= M) continue;
        float i0 = ind[0 * N_NODES + r];
        float i1 = ind[1 * N_NODES + r];
        float i2 = ind[2 * N_NODES + r];
        float v[8];
        #pragma unroll
        for (int j = 0; j < 8; ++j) {
            float t = acc[i][j] + i0 * bc[0][j] + i1 * bc[1][j] + i2 * bc[2][j];
            if (act) t = (t > 0.f) ? t : 0.01f * t;
            v[j] = t;
        }
        *(float4*)(out + (size_t)r * Dout + cb + tx * 4)      = make_float4(v[0], v[1], v[2], v[3]);
        *(float4*)(out + (size_t)r * Dout + cb + 64 + tx * 4) = make_float4(v[4], v[5], v[6], v[7]);
    }
}

// ---------------------------------------------------------------------------
// Launch
// ---------------------------------------------------------------------------
extern "C" void kernel_launch(void* const* d_in, const int* in_sizes, int n_in,
                              void* d_out, int out_size, void* d_ws, size_t ws_size,
                              hipStream_t stream) {
    const float* x      = (const float*)d_in[0];
    const int*   edges1 = (const int*)d_in[1];
    const int*   edges2 = (const int*)d_in[2];
    const float* W1     = (const float*)d_in[3];
    const float* b1     = (const float*)d_in[4];
    const float* W2     = (const float*)d_in[5];
    const float* b2     = (const float*)d_in[6];
    float* out = (float*)d_out;

    // workspace carve-up (~211 MB total)
    char* ws = (char*)d_ws;
    size_t p = 0;
    auto alloc = [&](size_t bytes) { size_t o = p; p = (p + bytes + 255) & ~(size_t)255; return o; };
    float* xbar   = (float*)(ws + alloc((size_t)N_NODES * KDIM * 4));     // 153.6 MB (xbar, then hbar)
    float* h      = (float*)(ws + alloc((size_t)N_NODES * D_HID * 4));    // 51.2 MB
    int*   cnt    = (int*)(ws + alloc((size_t)ET * N_NODES * 4));
    int*   rowptr = (int*)(ws + alloc((size_t)ET * (N_NODES + 1) * 4));
    int*   cursor = (int*)(ws + alloc((size_t)ET * N_NODES * 4));
    int*   esrc   = (int*)(ws + alloc((size_t)ET * N_EDGES * 4));
    float* ind    = (float*)(ws + alloc((size_t)ET * N_NODES * 4));
    (void)ws_size; (void)in_sizes; (void)n_in; (void)out_size;

    const int EB = (ET * N_EDGES + 255) / 256;       // 3516 blocks for edge kernels
    const int AB = (ET * N_NODES * 64 + 255) / 256;  // 37500 blocks for agg (1 wave/(e,n))
    const int MB = (N_NODES + BM - 1) / BM;          // 391 row-blocks

    // ---- layer 1 (graph 1) ----
    hipMemsetAsync(cnt, 0, (size_t)ET * N_NODES * 4, stream);
    hist_kernel<<<EB, 256, 0, stream>>>(edges1, cnt);
    scan_kernel<<<ET, 1024, 0, stream>>>(cnt, rowptr, cursor);
    fill_kernel<<<EB, 256, 0, stream>>>(edges1, cursor, esrc);
    agg_kernel<<<AB, 256, 0, stream>>>(x, rowptr, esrc, xbar, ind);
    gemm_kernel<<<dim3(MB, D_HID / BN), 256, 0, stream>>>(xbar, W1, b1, ind, h,
                                                          N_NODES, D_HID, 1);
    // ---- layer 2 (graph 2) ----
    hipMemsetAsync(cnt, 0, (size_t)ET * N_NODES * 4, stream);
    hist_kernel<<<EB, 256, 0, stream>>>(edges2, cnt);
    scan_kernel<<<ET, 1024, 0, stream>>>(cnt, rowptr, cursor);
    fill_kernel<<<EB, 256, 0, stream>>>(edges2, cursor, esrc);
    agg_kernel<<<AB, 256, 0, stream>>>(h, rowptr, esrc, xbar, ind);  // xbar reused as hbar
    gemm_kernel<<<dim3(MB, D_OUT / BN), 256, 0, stream>>>(xbar, W2, b2, ind, out,
                                                          N_NODES, D_OUT, 0);
}

// Round 4
// 829.140 us; speedup vs baseline: 1.3522x; 1.3522x over previous
//
#include <hip/hip_runtime.h>
#include <hip/hip_bf16.h>
#include <stdint.h>

// Problem constants (match reference)
#define N_NODES 50000
#define N_EDGES 300000
#define ET      3
#define D_IN    256
#define D_HID   256
#define D_OUT   128
#define KDIM    768          // ET * 256, fused-K for the single GEMM per layer
#define MPAD    50048        // 391 * 128 (GEMM row-tile padded)

typedef short bhalf8 __attribute__((ext_vector_type(8)));   // 8 bf16 (4 VGPRs)
typedef float f32x4  __attribute__((ext_vector_type(4)));

// bf16 helpers (RNE), bit-level to avoid header API differences
__device__ __forceinline__ unsigned short f2bf(float f) {
    union { float f; uint32_t u; } c; c.f = f;
    uint32_t u = c.u;
    uint32_t r = (u + 0x7fff + ((u >> 16) & 1)) >> 16;
    return (unsigned short)r;
}
__device__ __forceinline__ float bf2f(unsigned short b) {
    union { uint32_t u; float f; } c; c.u = ((uint32_t)b) << 16;
    return c.f;
}

__device__ __forceinline__ void glds16(const void* g, const void* l) {
    __builtin_amdgcn_global_load_lds(
        (const __attribute__((address_space(1))) unsigned int*)g,
        (__attribute__((address_space(3))) unsigned int*)l, 16, 0, 0);
}

// ---------------------------------------------------------------------------
// CSR build: histogram -> per-etype exclusive scan -> fill sorted src lists
// ---------------------------------------------------------------------------

__global__ void hist_kernel(const int* __restrict__ edges, int* __restrict__ cnt) {
    int i = blockIdx.x * blockDim.x + threadIdx.x;
    if (i >= ET * N_EDGES) return;
    int e = i / N_EDGES;
    int j = i - e * N_EDGES;
    int dst = edges[(e * 2 + 1) * N_EDGES + j];
    atomicAdd(&cnt[e * N_NODES + dst], 1);
}

__global__ void scan_kernel(const int* __restrict__ cnt, int* __restrict__ rowptr,
                            int* __restrict__ cursor) {
    int e = blockIdx.x;
    const int* c = cnt + e * N_NODES;
    int* rp = rowptr + e * (N_NODES + 1);
    int* cu = cursor + e * N_NODES;
    int t = threadIdx.x, lane = t & 63, w = t >> 6;
    __shared__ int wsum[16];
    __shared__ int carry;
    if (t == 0) carry = 0;
    __syncthreads();
    for (int base = 0; base < N_NODES; base += 1024) {
        int i = base + t;
        int orig = (i < N_NODES) ? c[i] : 0;
        int v = orig;
        #pragma unroll
        for (int d = 1; d < 64; d <<= 1) {
            int u = __shfl_up(v, d, 64);
            if (lane >= d) v += u;
        }
        if (lane == 63) wsum[w] = v;
        __syncthreads();
        if (w == 0 && lane < 16) {
            int s = wsum[lane];
            #pragma unroll
            for (int d = 1; d < 16; d <<= 1) {
                int u = __shfl_up(s, d, 64);
                if (lane >= d) s += u;
            }
            wsum[lane] = s;
        }
        __syncthreads();
        int woff = (w > 0) ? wsum[w - 1] : 0;
        int excl = carry + woff + (v - orig);
        if (i < N_NODES) { rp[i] = excl; cu[i] = excl; }
        __syncthreads();
        if (t == 0) carry += wsum[15];
        __syncthreads();
    }
    if (t == 0) rp[N_NODES] = carry;
}

__global__ void fill_kernel(const int* __restrict__ edges, int* __restrict__ cursor,
                            int* __restrict__ esrc) {
    int i = blockIdx.x * blockDim.x + threadIdx.x;
    if (i >= ET * N_EDGES) return;
    int e = i / N_EDGES;
    int j = i - e * N_EDGES;
    int src = edges[(e * 2 + 0) * N_EDGES + j];
    int dst = edges[(e * 2 + 1) * N_EDGES + j];
    int p = atomicAdd(&cursor[e * N_NODES + dst], 1);
    esrc[e * N_EDGES + p] = src;
}

// ---------------------------------------------------------------------------
// Aggregation (pull): one wave per (etype, node). Lane t owns channels
// [4t, 4t+4). Emits split-bf16 (hi/lo) directly into the GEMM's A layout:
// Xh/Xl[n][e*256 + c], row stride KDIM. ind[e][n] = (cnt>0).
// ---------------------------------------------------------------------------
__global__ void agg_kernel(const float* __restrict__ in, const int* __restrict__ rowptr,
                           const int* __restrict__ esrc,
                           unsigned short* __restrict__ Xh, unsigned short* __restrict__ Xl,
                           float* __restrict__ ind) {
    int wid = (blockIdx.x * blockDim.x + threadIdx.x) >> 6;
    int lane = threadIdx.x & 63;
    if (wid >= ET * N_NODES) return;
    int e = wid / N_NODES;
    int n = wid - e * N_NODES;
    int r0 = rowptr[e * (N_NODES + 1) + n];
    int r1 = rowptr[e * (N_NODES + 1) + n + 1];
    int cntv = r1 - r0;
    float4 acc = make_float4(0.f, 0.f, 0.f, 0.f);
    const int* es = esrc + e * N_EDGES;
    for (int j = r0; j < r1; ++j) {
        int s = es[j];  // wave-uniform
        float4 v = *((const float4*)(in + (size_t)s * 256) + lane);
        acc.x += v.x; acc.y += v.y; acc.z += v.z; acc.w += v.w;
    }
    float sc = (cntv > 0) ? (1.f / (float)cntv) : 0.f;
    acc.x *= sc; acc.y *= sc; acc.z *= sc; acc.w *= sc;
    ushort4 hv, lv;
    hv.x = f2bf(acc.x); lv.x = f2bf(acc.x - bf2f(hv.x));
    hv.y = f2bf(acc.y); lv.y = f2bf(acc.y - bf2f(hv.y));
    hv.z = f2bf(acc.z); lv.z = f2bf(acc.z - bf2f(hv.z));
    hv.w = f2bf(acc.w); lv.w = f2bf(acc.w - bf2f(hv.w));
    size_t o = (size_t)n * KDIM + e * 256 + lane * 4;
    *(ushort4*)(Xh + o) = hv;
    *(ushort4*)(Xl + o) = lv;
    if (lane == 0) ind[e * N_NODES + n] = (cntv > 0) ? 1.f : 0.f;
}

// ---------------------------------------------------------------------------
// W conversion: W[ET, Dout, 256] fp32 -> Wh/Wl[Dout, 768] bf16 (k = e*256+f)
// ---------------------------------------------------------------------------
__global__ void wconv_kernel(const float* __restrict__ W, unsigned short* __restrict__ Wh,
                             unsigned short* __restrict__ Wl, int Dout) {
    int i = blockIdx.x * blockDim.x + threadIdx.x;
    int total = ET * Dout * 256;
    if (i >= total) return;
    int f = i & 255;
    int t = i >> 8;            // e*Dout + co
    int e = t / Dout;
    int co = t - e * Dout;
    float w = W[i];
    unsigned short h = f2bf(w);
    float rem = w - bf2f(h);
    unsigned short l = f2bf(rem);
    int o = co * KDIM + e * 256 + f;
    Wh[o] = h; Wl[o] = l;
}

// ---------------------------------------------------------------------------
// Split-bf16 MFMA GEMM: out[M,Dout] = X[M,768] @ W[Dout,768]^T
//   acc += Ah*Bh + Ah*Bl + Al*Bh   (Al*Bl dropped, ~2^-18 relative)
// 128x128 tile, BK=32, 4 waves (2x2), each wave 64x64 = 4x4 fragments of
// 16x16x32. LDS is fragment-linear: chunk(arr, sub) = 16 rows x 32 K stored
// as 64 contiguous 16B lane-slots -> global_load_lds staging and ds_read_b128
// reads are both perfectly linear (conflict-free by construction).
// Epilogue: + sum_e ind[e][row]*bias[e][col], ACT=1 -> leaky_relu(0.01).
// ---------------------------------------------------------------------------
template<int ACT>
__global__ __launch_bounds__(256) void mfma_gemm(
    const unsigned short* __restrict__ Xh, const unsigned short* __restrict__ Xl,
    const unsigned short* __restrict__ Wh, const unsigned short* __restrict__ Wl,
    const float* __restrict__ bias, const float* __restrict__ ind,
    float* __restrict__ out, int M, int Dout) {
    // 32 KB: Ah[8 chunks] Al Bh Bl, each chunk 512 ushorts (16 rows x 32 K)
    __shared__ __align__(16) unsigned short smem[16384];
    const int tid  = threadIdx.x;
    const int lane = tid & 63;
    const int wid  = tid >> 6;           // 0..3
    const int wr   = wid >> 1, wc = wid & 1;
    const int rb   = blockIdx.x * 128;
    const int cb   = blockIdx.y * 128;
    const int lrow = lane & 15;
    const int lcol = (lane >> 4) * 8;    // bf16 element offset within 32-K

    f32x4 acc[4][4];
    #pragma unroll
    for (int i = 0; i < 4; ++i)
        #pragma unroll
        for (int j = 0; j < 4; ++j)
            acc[i][j] = (f32x4){0.f, 0.f, 0.f, 0.f};

    // staging pointers: wave stages subs {2*wid, 2*wid+1} of each array
    const unsigned short* ga_h[2];
    const unsigned short* ga_l[2];
    const unsigned short* gb_h[2];
    const unsigned short* gb_l[2];
    #pragma unroll
    for (int s = 0; s < 2; ++s) {
        int sub  = 2 * wid + s;
        size_t ao = (size_t)(rb + sub * 16 + lrow) * KDIM + lcol;  // rows < MPAD
        size_t bo = (size_t)(cb + sub * 16 + lrow) * KDIM + lcol;
        ga_h[s] = Xh + ao;  ga_l[s] = Xl + ao;
        gb_h[s] = Wh + bo;  gb_l[s] = Wl + bo;
    }

    for (int k0 = 0; k0 < KDIM; k0 += 32) {
        #pragma unroll
        for (int s = 0; s < 2; ++s) {
            int sub = 2 * wid + s;
            glds16(ga_h[s] + k0, &smem[0 * 4096 + sub * 512]);
            glds16(ga_l[s] + k0, &smem[1 * 4096 + sub * 512]);
            glds16(gb_h[s] + k0, &smem[2 * 4096 + sub * 512]);
            glds16(gb_l[s] + k0, &smem[3 * 4096 + sub * 512]);
        }
        __syncthreads();

        bhalf8 ah[4], al[4], bh[4], bl[4];
        #pragma unroll
        for (int t = 0; t < 4; ++t) {
            ah[t] = *(const bhalf8*)&smem[0 * 4096 + (wr * 4 + t) * 512 + lane * 8];
            al[t] = *(const bhalf8*)&smem[1 * 4096 + (wr * 4 + t) * 512 + lane * 8];
            bh[t] = *(const bhalf8*)&smem[2 * 4096 + (wc * 4 + t) * 512 + lane * 8];
            bl[t] = *(const bhalf8*)&smem[3 * 4096 + (wc * 4 + t) * 512 + lane * 8];
        }
        #pragma unroll
        for (int i = 0; i < 4; ++i)
            #pragma unroll
            for (int j = 0; j < 4; ++j) {
                acc[i][j] = __builtin_amdgcn_mfma_f32_16x16x32_bf16(ah[i], bh[j], acc[i][j], 0, 0, 0);
                acc[i][j] = __builtin_amdgcn_mfma_f32_16x16x32_bf16(ah[i], bl[j], acc[i][j], 0, 0, 0);
                acc[i][j] = __builtin_amdgcn_mfma_f32_16x16x32_bf16(al[i], bh[j], acc[i][j], 0, 0, 0);
            }
        __syncthreads();
    }

    // epilogue: C/D layout col=lane&15, row=(lane>>4)*4+reg
    const int orow = (lane >> 4) * 4;
    const int ocol = lane & 15;
    #pragma unroll
    for (int i = 0; i < 4; ++i) {
        int rbase = rb + wr * 64 + i * 16 + orow;
        #pragma unroll
        for (int q = 0; q < 4; ++q) {
            int r = rbase + q;
            if (r >= M) continue;
            float i0 = ind[0 * N_NODES + r];
            float i1 = ind[1 * N_NODES + r];
            float i2 = ind[2 * N_NODES + r];
            #pragma unroll
            for (int j = 0; j < 4; ++j) {
                int col = cb + wc * 64 + j * 16 + ocol;
                float t = acc[i][j][q] + i0 * bias[0 * Dout + col]
                                       + i1 * bias[1 * Dout + col]
                                       + i2 * bias[2 * Dout + col];
                if (ACT) t = (t > 0.f) ? t : 0.01f * t;
                out[(size_t)r * Dout + col] = t;
            }
        }
    }
}

// ---------------------------------------------------------------------------
// Launch
// ---------------------------------------------------------------------------
extern "C" void kernel_launch(void* const* d_in, const int* in_sizes, int n_in,
                              void* d_out, int out_size, void* d_ws, size_t ws_size,
                              hipStream_t stream) {
    const float* x      = (const float*)d_in[0];
    const int*   edges1 = (const int*)d_in[1];
    const int*   edges2 = (const int*)d_in[2];
    const float* W1     = (const float*)d_in[3];
    const float* b1     = (const float*)d_in[4];
    const float* W2     = (const float*)d_in[5];
    const float* b2     = (const float*)d_in[6];
    float* out = (float*)d_out;

    // workspace carve-up (~213 MB)
    char* ws = (char*)d_ws;
    size_t p = 0;
    auto alloc = [&](size_t bytes) { size_t o = p; p = (p + bytes + 255) & ~(size_t)255; return o; };
    unsigned short* Xh  = (unsigned short*)(ws + alloc((size_t)MPAD * KDIM * 2));  // 76.9 MB
    unsigned short* Xl  = (unsigned short*)(ws + alloc((size_t)MPAD * KDIM * 2));  // 76.9 MB
    float* h            = (float*)(ws + alloc((size_t)N_NODES * D_HID * 4));       // 51.2 MB
    unsigned short* W1h = (unsigned short*)(ws + alloc((size_t)D_HID * KDIM * 2));
    unsigned short* W1l = (unsigned short*)(ws + alloc((size_t)D_HID * KDIM * 2));
    unsigned short* W2h = (unsigned short*)(ws + alloc((size_t)D_OUT * KDIM * 2));
    unsigned short* W2l = (unsigned short*)(ws + alloc((size_t)D_OUT * KDIM * 2));
    int*   cnt    = (int*)(ws + alloc((size_t)ET * N_NODES * 4));
    int*   rowptr = (int*)(ws + alloc((size_t)ET * (N_NODES + 1) * 4));
    int*   cursor = (int*)(ws + alloc((size_t)ET * N_NODES * 4));
    int*   esrc   = (int*)(ws + alloc((size_t)ET * N_EDGES * 4));
    float* ind    = (float*)(ws + alloc((size_t)ET * N_NODES * 4));
    (void)ws_size; (void)in_sizes; (void)n_in; (void)out_size;

    const int EB = (ET * N_EDGES + 255) / 256;
    const int AB = (ET * N_NODES * 64 + 255) / 256;
    const int MB = MPAD / 128;   // 391

    // weight split (once per call; graph-capture-safe, pure kernels)
    wconv_kernel<<<(ET * D_HID * 256 + 255) / 256, 256, 0, stream>>>(W1, W1h, W1l, D_HID);
    wconv_kernel<<<(ET * D_OUT * 256 + 255) / 256, 256, 0, stream>>>(W2, W2h, W2l, D_OUT);

    // ---- layer 1 (graph 1) ----
    hipMemsetAsync(cnt, 0, (size_t)ET * N_NODES * 4, stream);
    hist_kernel<<<EB, 256, 0, stream>>>(edges1, cnt);
    scan_kernel<<<ET, 1024, 0, stream>>>(cnt, rowptr, cursor);
    fill_kernel<<<EB, 256, 0, stream>>>(edges1, cursor, esrc);
    agg_kernel<<<AB, 256, 0, stream>>>(x, rowptr, esrc, Xh, Xl, ind);
    mfma_gemm<1><<<dim3(MB, D_HID / 128), 256, 0, stream>>>(Xh, Xl, W1h, W1l, b1, ind, h,
                                                            N_NODES, D_HID);
    // ---- layer 2 (graph 2) ----
    hipMemsetAsync(cnt, 0, (size_t)ET * N_NODES * 4, stream);
    hist_kernel<<<EB, 256, 0, stream>>>(edges2, cnt);
    scan_kernel<<<ET, 1024, 0, stream>>>(cnt, rowptr, cursor);
    fill_kernel<<<EB, 256, 0, stream>>>(edges2, cursor, esrc);
    agg_kernel<<<AB, 256, 0, stream>>>(h, rowptr, esrc, Xh, Xl, ind);
    mfma_gemm<0><<<dim3(MB, D_OUT / 128), 256, 0, stream>>>(Xh, Xl, W2h, W2l, b2, ind, out,
                                                            N_NODES, D_OUT);
}

// Round 7
// 731.191 us; speedup vs baseline: 1.5333x; 1.1340x over previous
//
#include <hip/hip_runtime.h>
#include <hip/hip_bf16.h>
#include <stdint.h>

// Problem constants (match reference)
#define N_NODES 50000
#define N_EDGES 300000
#define ET      3
#define D_IN    256
#define D_HID   256
#define D_OUT   128
#define KDIM    768          // ET * 256, fused-K for the single GEMM per layer
#define MPAD    50048        // 391 * 128 (GEMM row-tile padded)
#define NTOT    (ET * N_NODES)          // 150000 merged (etype,node) slots
#define ETOT    (ET * N_EDGES)          // 900000 edges total
#define NB1     ((NTOT + 1023) / 1024)  // 147 scan blocks

typedef short bhalf8 __attribute__((ext_vector_type(8)));   // 8 bf16 (4 VGPRs)
typedef float f32x4  __attribute__((ext_vector_type(4)));

// bf16 helpers (RNE), bit-level to avoid header API differences
__device__ __forceinline__ unsigned short f2bf(float f) {
    union { float f; uint32_t u; } c; c.f = f;
    uint32_t u = c.u;
    uint32_t r = (u + 0x7fff + ((u >> 16) & 1)) >> 16;
    return (unsigned short)r;
}
__device__ __forceinline__ float bf2f(unsigned short b) {
    union { uint32_t u; float f; } c; c.u = ((uint32_t)b) << 16;
    return c.f;
}

__device__ __forceinline__ void glds16(const void* g, const void* l) {
    __builtin_amdgcn_global_load_lds(
        (const __attribute__((address_space(1))) unsigned int*)g,
        (__attribute__((address_space(3))) unsigned int*)l, 16, 0, 0);
}

// ---------------------------------------------------------------------------
// CSR build (merged across etypes): histogram -> 3-kernel parallel scan ->
// fill. One global exclusive scan of cnt[150000]; per-etype bases are
// implicit (each etype contributes exactly N_EDGES).
// ---------------------------------------------------------------------------

__global__ void hist_kernel(const int* __restrict__ edges, int* __restrict__ cnt) {
    int i = blockIdx.x * blockDim.x + threadIdx.x;
    if (i >= ETOT) return;
    int e = i / N_EDGES;
    int j = i - e * N_EDGES;
    int dst = edges[(e * 2 + 1) * N_EDGES + j];
    atomicAdd(&cnt[e * N_NODES + dst], 1);
}

// scan1: block b scans its 1024 counts (4/thread), writes block-local
// exclusive positions into rp and the block total into bsum[b].
__global__ __launch_bounds__(256) void scan1_kernel(const int* __restrict__ cnt,
                                                    int* __restrict__ rp,
                                                    int* __restrict__ bsum) {
    int b = blockIdx.x, t = threadIdx.x;
    int idx = b * 1024 + t * 4;
    int4 v = make_int4(0, 0, 0, 0);
    if (idx + 3 < NTOT) v = *(const int4*)&cnt[idx];
    else {
        if (idx + 0 < NTOT) v.x = cnt[idx + 0];
        if (idx + 1 < NTOT) v.y = cnt[idx + 1];
        if (idx + 2 < NTOT) v.z = cnt[idx + 2];
        if (idx + 3 < NTOT) v.w = cnt[idx + 3];
    }
    int s = v.x + v.y + v.z + v.w;
    int lane = t & 63, w = t >> 6;
    int inc = s;
    #pragma unroll
    for (int d = 1; d < 64; d <<= 1) {
        int u = __shfl_up(inc, d, 64);
        if (lane >= d) inc += u;
    }
    __shared__ int ws[4];
    if (lane == 63) ws[w] = inc;
    __syncthreads();
    int wbase = 0;
    for (int i = 0; i < w; ++i) wbase += ws[i];
    int ebase = wbase + inc - s;   // block-local exclusive base for this thread
    if (idx + 0 < NTOT) rp[idx + 0] = ebase;
    if (idx + 1 < NTOT) rp[idx + 1] = ebase + v.x;
    if (idx + 2 < NTOT) rp[idx + 2] = ebase + v.x + v.y;
    if (idx + 3 < NTOT) rp[idx + 3] = ebase + v.x + v.y + v.z;
    if (t == 0) bsum[b] = ws[0] + ws[1] + ws[2] + ws[3];
}

// scan2: one block; exclusive scan of the 147 block sums (Hillis-Steele).
__global__ __launch_bounds__(256) void scan2_kernel(const int* __restrict__ bsum,
                                                    int* __restrict__ bbase) {
    int t = threadIdx.x;
    __shared__ int sh[256];
    int v = (t < NB1) ? bsum[t] : 0;
    sh[t] = v;
    __syncthreads();
    #pragma unroll
    for (int d = 1; d < 256; d <<= 1) {
        int u = (t >= d) ? sh[t - d] : 0;
        __syncthreads();
        sh[t] += u;
        __syncthreads();
    }
    if (t < NB1) bbase[t] = sh[t] - v;   // exclusive
}

// scan3: add block bases; emit final rowptr + cursor copy + sentinel.
__global__ void scan3_kernel(int* __restrict__ rp, int* __restrict__ cursor,
                             const int* __restrict__ bbase) {
    int i = blockIdx.x * blockDim.x + threadIdx.x;
    if (i < NTOT) {
        int v = rp[i] + bbase[i >> 10];
        rp[i] = v;
        cursor[i] = v;
    }
    if (i == 0) rp[NTOT] = ETOT;
}

__global__ void fill_kernel(const int* __restrict__ edges, int* __restrict__ cursor,
                            int* __restrict__ esrc) {
    int i = blockIdx.x * blockDim.x + threadIdx.x;
    if (i >= ETOT) return;
    int e = i / N_EDGES;
    int j = i - e * N_EDGES;
    int src = edges[(e * 2 + 0) * N_EDGES + j];
    int dst = edges[(e * 2 + 1) * N_EDGES + j];
    int p = atomicAdd(&cursor[e * N_NODES + dst], 1);   // global position
    esrc[p] = src;
}

// ---------------------------------------------------------------------------
// Aggregation (pull): one wave per (etype, node). Lane t owns channels
// [4t, 4t+4). Emits split-bf16 (hi/lo) directly into the GEMM's A layout:
// Xh/Xl[n][e*256 + c], row stride KDIM. ind[e*N+n] = (cnt>0).
// ---------------------------------------------------------------------------
__global__ void agg_kernel(const float* __restrict__ in, const int* __restrict__ rp,
                           const int* __restrict__ esrc,
                           unsigned short* __restrict__ Xh, unsigned short* __restrict__ Xl,
                           float* __restrict__ ind) {
    int wid = (blockIdx.x * blockDim.x + threadIdx.x) >> 6;
    int lane = threadIdx.x & 63;
    if (wid >= NTOT) return;
    int e = wid / N_NODES;
    int n = wid - e * N_NODES;
    int r0 = rp[wid];
    int r1 = rp[wid + 1];
    int cntv = r1 - r0;
    float4 acc = make_float4(0.f, 0.f, 0.f, 0.f);
    for (int j = r0; j < r1; ++j) {
        int s = esrc[j];  // wave-uniform
        float4 v = *((const float4*)(in + (size_t)s * 256) + lane);
        acc.x += v.x; acc.y += v.y; acc.z += v.z; acc.w += v.w;
    }
    float sc = (cntv > 0) ? (1.f / (float)cntv) : 0.f;
    acc.x *= sc; acc.y *= sc; acc.z *= sc; acc.w *= sc;
    ushort4 hv, lv;
    hv.x = f2bf(acc.x); lv.x = f2bf(acc.x - bf2f(hv.x));
    hv.y = f2bf(acc.y); lv.y = f2bf(acc.y - bf2f(hv.y));
    hv.z = f2bf(acc.z); lv.z = f2bf(acc.z - bf2f(hv.z));
    hv.w = f2bf(acc.w); lv.w = f2bf(acc.w - bf2f(hv.w));
    size_t o = (size_t)n * KDIM + e * 256 + lane * 4;
    *(ushort4*)(Xh + o) = hv;
    *(ushort4*)(Xl + o) = lv;
    if (lane == 0) ind[wid] = (cntv > 0) ? 1.f : 0.f;
}

// ---------------------------------------------------------------------------
// W conversion: W[ET, Dout, 256] fp32 -> Wh/Wl[Dout, 768] bf16 (k = e*256+f)
// ---------------------------------------------------------------------------
__global__ void wconv_kernel(const float* __restrict__ W, unsigned short* __restrict__ Wh,
                             unsigned short* __restrict__ Wl, int Dout) {
    int i = blockIdx.x * blockDim.x + threadIdx.x;
    int total = ET * Dout * 256;
    if (i >= total) return;
    int f = i & 255;
    int t = i >> 8;            // e*Dout + co
    int e = t / Dout;
    int co = t - e * Dout;
    float w = W[i];
    unsigned short h = f2bf(w);
    float rem = w - bf2f(h);
    unsigned short l = f2bf(rem);
    int o = co * KDIM + e * 256 + f;
    Wh[o] = h; Wl[o] = l;
}

// ---------------------------------------------------------------------------
// Split-bf16 MFMA GEMM: out[M,Dout] = X[M,768] @ W[Dout,768]^T
//   acc += Ah*Bh + Ah*Bl + Al*Bh   (Al*Bl dropped, ~2^-18 relative)
// 128x128 tile, BK=32, 4 waves (2x2), each wave 64x64 = 4x4 fragments of
// 16x16x32. LDS fragment-linear (conflict-free by construction), DOUBLE-
// BUFFERED: stage K-step t+1 while computing t; one barrier per K-step
// (compiler emits the vmcnt/lgkmcnt drain at the barrier).
// Epilogue: + sum_e ind[e][row]*bias[e][col], ACT=1 -> leaky_relu(0.01).
// ---------------------------------------------------------------------------
template<int ACT>
__global__ __launch_bounds__(256) void mfma_gemm(
    const unsigned short* __restrict__ Xh, const unsigned short* __restrict__ Xl,
    const unsigned short* __restrict__ Wh, const unsigned short* __restrict__ Wl,
    const float* __restrict__ bias, const float* __restrict__ ind,
    float* __restrict__ out, int M, int Dout) {
    // 2 x 32 KB halves: [Ah | Al | Bh | Bl] x 8 chunks x 512 ushorts
    __shared__ __align__(16) unsigned short smem[2 * 16384];
    const int tid  = threadIdx.x;
    const int lane = tid & 63;
    const int wid  = tid >> 6;           // 0..3
    const int wr   = wid >> 1, wc = wid & 1;
    const int rb   = blockIdx.x * 128;
    const int cb   = blockIdx.y * 128;
    const int lrow = lane & 15;
    const int lcol = (lane >> 4) * 8;    // bf16 element offset within 32-K

    f32x4 acc[4][4];
    #pragma unroll
    for (int i = 0; i < 4; ++i)
        #pragma unroll
        for (int j = 0; j < 4; ++j)
            acc[i][j] = (f32x4){0.f, 0.f, 0.f, 0.f};

    // staging pointers: wave stages subs {2*wid, 2*wid+1} of each array
    const unsigned short* ga_h[2];
    const unsigned short* ga_l[2];
    const unsigned short* gb_h[2];
    const unsigned short* gb_l[2];
    #pragma unroll
    for (int s = 0; s < 2; ++s) {
        int sub  = 2 * wid + s;
        size_t ao = (size_t)(rb + sub * 16 + lrow) * KDIM + lcol;  // rows < MPAD
        size_t bo = (size_t)(cb + sub * 16 + lrow) * KDIM + lcol;
        ga_h[s] = Xh + ao;  ga_l[s] = Xl + ao;
        gb_h[s] = Wh + bo;  gb_l[s] = Wl + bo;
    }

    // prologue: stage K-step 0 into half 0
    #pragma unroll
    for (int s = 0; s < 2; ++s) {
        int sub = 2 * wid + s;
        glds16(ga_h[s], &smem[0 * 4096 + sub * 512]);
        glds16(ga_l[s], &smem[1 * 4096 + sub * 512]);
        glds16(gb_h[s], &smem[2 * 4096 + sub * 512]);
        glds16(gb_l[s], &smem[3 * 4096 + sub * 512]);
    }
    __syncthreads();

    int cur = 0;
    for (int t = 0; t < KDIM / 32; ++t) {
        // stage next K-step into the other half (hidden under MFMA below)
        if (t < KDIM / 32 - 1) {
            unsigned short* sb = &smem[(cur ^ 1) * 16384];
            int nk = (t + 1) * 32;
            #pragma unroll
            for (int s = 0; s < 2; ++s) {
                int sub = 2 * wid + s;
                glds16(ga_h[s] + nk, &sb[0 * 4096 + sub * 512]);
                glds16(ga_l[s] + nk, &sb[1 * 4096 + sub * 512]);
                glds16(gb_h[s] + nk, &sb[2 * 4096 + sub * 512]);
                glds16(gb_l[s] + nk, &sb[3 * 4096 + sub * 512]);
            }
        }
        const unsigned short* sc = &smem[cur * 16384];
        bhalf8 ah[4], al[4], bh[4], bl[4];
        #pragma unroll
        for (int q = 0; q < 4; ++q) {
            ah[q] = *(const bhalf8*)&sc[0 * 4096 + (wr * 4 + q) * 512 + lane * 8];
            al[q] = *(const bhalf8*)&sc[1 * 4096 + (wr * 4 + q) * 512 + lane * 8];
            bh[q] = *(const bhalf8*)&sc[2 * 4096 + (wc * 4 + q) * 512 + lane * 8];
            bl[q] = *(const bhalf8*)&sc[3 * 4096 + (wc * 4 + q) * 512 + lane * 8];
        }
        #pragma unroll
        for (int i = 0; i < 4; ++i)
            #pragma unroll
            for (int j = 0; j < 4; ++j) {
                acc[i][j] = __builtin_amdgcn_mfma_f32_16x16x32_bf16(ah[i], bh[j], acc[i][j], 0, 0, 0);
                acc[i][j] = __builtin_amdgcn_mfma_f32_16x16x32_bf16(ah[i], bl[j], acc[i][j], 0, 0, 0);
                acc[i][j] = __builtin_amdgcn_mfma_f32_16x16x32_bf16(al[i], bh[j], acc[i][j], 0, 0, 0);
            }
        __syncthreads();
        cur ^= 1;
    }

    // epilogue: C/D layout col=lane&15, row=(lane>>4)*4+reg
    const int orow = (lane >> 4) * 4;
    const int ocol = lane & 15;
    #pragma unroll
    for (int i = 0; i < 4; ++i) {
        int rbase = rb + wr * 64 + i * 16 + orow;
        #pragma unroll
        for (int q = 0; q < 4; ++q) {
            int r = rbase + q;
            if (r >= M) continue;
            float i0 = ind[0 * N_NODES + r];
            float i1 = ind[1 * N_NODES + r];
            float i2 = ind[2 * N_NODES + r];
            #pragma unroll
            for (int j = 0; j < 4; ++j) {
                int col = cb + wc * 64 + j * 16 + ocol;
                float t = acc[i][j][q] + i0 * bias[0 * Dout + col]
                                       + i1 * bias[1 * Dout + col]
                                       + i2 * bias[2 * Dout + col];
                if (ACT) t = (t > 0.f) ? t : 0.01f * t;
                out[(size_t)r * Dout + col] = t;
            }
        }
    }
}

// ---------------------------------------------------------------------------
// Launch
// ---------------------------------------------------------------------------
extern "C" void kernel_launch(void* const* d_in, const int* in_sizes, int n_in,
                              void* d_out, int out_size, void* d_ws, size_t ws_size,
                              hipStream_t stream) {
    const float* x      = (const float*)d_in[0];
    const int*   edges1 = (const int*)d_in[1];
    const int*   edges2 = (const int*)d_in[2];
    const float* W1     = (const float*)d_in[3];
    const float* b1     = (const float*)d_in[4];
    const float* W2     = (const float*)d_in[5];
    const float* b2     = (const float*)d_in[6];
    float* out = (float*)d_out;

    // workspace carve-up (~213 MB)
    char* ws = (char*)d_ws;
    size_t p = 0;
    auto alloc = [&](size_t bytes) { size_t o = p; p = (p + bytes + 255) & ~(size_t)255; return o; };
    unsigned short* Xh  = (unsigned short*)(ws + alloc((size_t)MPAD * KDIM * 2));  // 76.9 MB
    unsigned short* Xl  = (unsigned short*)(ws + alloc((size_t)MPAD * KDIM * 2));  // 76.9 MB
    float* h            = (float*)(ws + alloc((size_t)N_NODES * D_HID * 4));       // 51.2 MB
    unsigned short* W1h = (unsigned short*)(ws + alloc((size_t)D_HID * KDIM * 2));
    unsigned short* W1l = (unsigned short*)(ws + alloc((size_t)D_HID * KDIM * 2));
    unsigned short* W2h = (unsigned short*)(ws + alloc((size_t)D_OUT * KDIM * 2));
    unsigned short* W2l = (unsigned short*)(ws + alloc((size_t)D_OUT * KDIM * 2));
    int*   cnt    = (int*)(ws + alloc((size_t)NTOT * 4));
    int*   rp     = (int*)(ws + alloc((size_t)(NTOT + 1) * 4));
    int*   cursor = (int*)(ws + alloc((size_t)NTOT * 4));
    int*   esrc   = (int*)(ws + alloc((size_t)ETOT * 4));
    float* ind    = (float*)(ws + alloc((size_t)NTOT * 4));
    int*   bsum   = (int*)(ws + alloc(256 * 4));
    int*   bbase  = (int*)(ws + alloc(256 * 4));
    (void)ws_size; (void)in_sizes; (void)n_in; (void)out_size;

    const int EB = (ETOT + 255) / 256;
    const int AB = (NTOT * 64 + 255) / 256;
    const int MB = MPAD / 128;   // 391
    const int S3 = (NTOT + 255) / 256;

    // weight split (once per call; graph-capture-safe, pure kernels)
    wconv_kernel<<<(ET * D_HID * 256 + 255) / 256, 256, 0, stream>>>(W1, W1h, W1l, D_HID);
    wconv_kernel<<<(ET * D_OUT * 256 + 255) / 256, 256, 0, stream>>>(W2, W2h, W2l, D_OUT);

    // ---- layer 1 (graph 1) ----
    hipMemsetAsync(cnt, 0, (size_t)NTOT * 4, stream);
    hist_kernel<<<EB, 256, 0, stream>>>(edges1, cnt);
    scan1_kernel<<<NB1, 256, 0, stream>>>(cnt, rp, bsum);
    scan2_kernel<<<1, 256, 0, stream>>>(bsum, bbase);
    scan3_kernel<<<S3, 256, 0, stream>>>(rp, cursor, bbase);
    fill_kernel<<<EB, 256, 0, stream>>>(edges1, cursor, esrc);
    agg_kernel<<<AB, 256, 0, stream>>>(x, rp, esrc, Xh, Xl, ind);
    mfma_gemm<1><<<dim3(MB, D_HID / 128), 256, 0, stream>>>(Xh, Xl, W1h, W1l, b1, ind, h,
                                                            N_NODES, D_HID);
    // ---- layer 2 (graph 2) ----
    hipMemsetAsync(cnt, 0, (size_t)NTOT * 4, stream);
    hist_kernel<<<EB, 256, 0, stream>>>(edges2, cnt);
    scan1_kernel<<<NB1, 256, 0, stream>>>(cnt, rp, bsum);
    scan2_kernel<<<1, 256, 0, stream>>>(bsum, bbase);
    scan3_kernel<<<S3, 256, 0, stream>>>(rp, cursor, bbase);
    fill_kernel<<<EB, 256, 0, stream>>>(edges2, cursor, esrc);
    agg_kernel<<<AB, 256, 0, stream>>>(h, rp, esrc, Xh, Xl, ind);
    mfma_gemm<0><<<dim3(MB, D_OUT / 128), 256, 0, stream>>>(Xh, Xl, W2h, W2l, b2, ind, out,
                                                            N_NODES, D_OUT);
}